// Round 12
// baseline (383.139 us; speedup 1.0000x reference)
//
#include <hip/hip_runtime.h>

// ---------------- types & helpers ----------------
typedef __bf16 bf16x8 __attribute__((ext_vector_type(8)));
typedef float f32x4 __attribute__((ext_vector_type(4)));
typedef unsigned short us_t;

#define DEV __device__ __forceinline__

DEV float bf2f(unsigned short u) {
  union { unsigned int i; float f; } c; c.i = ((unsigned int)u) << 16; return c.f;
}
DEV unsigned short f2bf(float f) {
  union { float f; unsigned int i; } c; c.f = f;
  return (unsigned short)((c.i + 0x7FFFu + ((c.i >> 16) & 1u)) >> 16);
}
DEV unsigned int cvt_pk_bf16(float lo, float hi) {
  unsigned int r;
  asm("v_cvt_pk_bf16_f32 %0, %1, %2" : "=v"(r) : "v"(lo), "v"(hi));
  return r;
}

union FragU { bf16x8 v; unsigned short u[8]; };

DEV void gld_lds16(const void* g, void* l) {
  __builtin_amdgcn_global_load_lds((const __attribute__((address_space(1))) void*)g,
                                   (__attribute__((address_space(3))) void*)l, 16, 0, 0);
}

#define MFMA(a, b, c) __builtin_amdgcn_mfma_f32_16x16x32_bf16((a), (b), (c), 0, 0, 0)

// ---------------- problem constants ----------------
#define BB 8
#define NN 1569
#define DD 768
#define HH 12
#define DH 64
#define FF 8
#define NFR 196
#define NTT 77
#define DT_ 512
#define MROWS 12552   // B*N
#define MTEXT 616     // B*NT

// ---------------- fused fp32 -> bf16 convert (x then y) ----------------
__global__ void cvt_fused(const float* __restrict__ xin, unsigned short* __restrict__ xout, int n4x,
                          const float* __restrict__ yin, unsigned short* __restrict__ yout, int n4y) {
  int i = blockIdx.x * blockDim.x + threadIdx.x;
  int stride = gridDim.x * blockDim.x;
  int total = n4x + n4y;
  for (; i < total; i += stride) {
    const float4* src; ushort4* dst; int idx;
    if (i < n4x) { src = (const float4*)xin; dst = (ushort4*)xout; idx = i; }
    else         { src = (const float4*)yin; dst = (ushort4*)yout; idx = i - n4x; }
    float4 v = src[idx];
    ushort4 o;
    o.x = f2bf(v.x); o.y = f2bf(v.y); o.z = f2bf(v.z); o.w = f2bf(v.w);
    dst[idx] = o;
  }
}

// ---------------- fused transpose + convert: out[C][R] = in[R][C], 5 jobs ----------------
struct TJobs {
  const float* in[5];
  unsigned short* out[5];
  int R[5], C[5];
};

__global__ __launch_bounds__(256) void transpose_all(TJobs j) {
  __shared__ float tile[32][33];
  int z = blockIdx.z;
  int R = j.R[z], C = j.C[z];
  int bx = blockIdx.x * 32;   // C base
  int by = blockIdx.y * 32;   // R base
  if (bx >= C || by >= R) return;
  const float* in = j.in[z];
  unsigned short* out = j.out[z];
  int tx = threadIdx.x & 31;
  int ty0 = threadIdx.x >> 5; // 0..7
  for (int dy = 0; dy < 32; dy += 8) {
    int r = by + ty0 + dy, c = bx + tx;
    tile[ty0 + dy][tx] = (r < R && c < C) ? in[(size_t)r * C + c] : 0.f;
  }
  __syncthreads();
  for (int dy = 0; dy < 32; dy += 8) {
    int orow = bx + ty0 + dy;  // C index
    int ocol = by + tx;        // R index
    if (orow < C && ocol < R) out[(size_t)orow * R + ocol] = f2bf(tile[tx][ty0 + dy]);
  }
}

// ---------------- epilogue kinds ----------------
enum { EPI_QKV = 0, EPI_XOUT = 1, EPI_QI = 2, EPI_KVT = 3, EPI_FINAL = 4 };

struct EpiParams {
  float* outf;
  unsigned short *o0, *o1, *o2;
  const float *bias, *aux, *alphap;
};

// =====================================================================
// 128x128 GEMM, ring-3 ONE-barrier pipeline (r11, perf == r8 ring-3).
// Used for the 768-col GEMMs + KVT.
// =====================================================================
template <int EPI>
__global__ __launch_bounds__(256)
void gemm_bt(const unsigned short* __restrict__ A, const unsigned short* __restrict__ Bt,
             int M, int K, EpiParams ep) {
  __shared__ __align__(16) unsigned short lA[3][128 * 32];
  __shared__ __align__(16) unsigned short lB[3][128 * 32];
  const int nbx = gridDim.x, nwg = gridDim.x * gridDim.y;
  int flat = blockIdx.y * nbx + blockIdx.x;
  {
    int q = nwg >> 3, r = nwg & 7;
    int xcd = flat & 7, i = flat >> 3;
    flat = (xcd < r ? xcd * (q + 1) : r * (q + 1) + (xcd - r) * q) + i;
  }
  const int brow = (flat / nbx) * 128, bcol = (flat % nbx) * 128;
  const int t = threadIdx.x, wave = t >> 6, lane = t & 63, g = lane >> 4, l15 = lane & 15;
  const int wr = wave >> 1, wc = wave & 1;

  int dsto[2];
  const unsigned short *pA[2], *pB[2];
#pragma unroll
  for (int c = 0; c < 2; ++c) {
    int sb = wave * 1024 + c * 512;
    int slot = sb + lane * 8;
    int row = slot >> 5;
    int gl = (slot >> 3) & 3;
    int swz = gl ^ ((row >> 1) & 3);
    int ra = brow + row; if (ra > M - 1) ra = M - 1;
    dsto[c] = sb;
    pA[c] = A + (size_t)ra * K + swz * 8;
    pB[c] = Bt + (size_t)(bcol + row) * K + swz * 8;
  }

#define STG(s, k0) do { \
    gld_lds16(pA[0] + (k0), &lA[s][dsto[0]]); \
    gld_lds16(pB[0] + (k0), &lB[s][dsto[0]]); \
    gld_lds16(pA[1] + (k0), &lA[s][dsto[1]]); \
    gld_lds16(pB[1] + (k0), &lB[s][dsto[1]]); \
    __builtin_amdgcn_sched_barrier(0); } while (0)

  f32x4 acc[4][4];
#pragma unroll
  for (int i = 0; i < 4; ++i)
#pragma unroll
    for (int j = 0; j < 4; ++j) acc[i][j] = {0.f, 0.f, 0.f, 0.f};

  const int nk = K >> 5;
  STG(0, 0);
  if (nk > 1) STG(1, 32);

  for (int kt = 0; kt < nk; ++kt) {
    const int s = kt % 3;
    if (kt + 1 < nk) { asm volatile("s_waitcnt vmcnt(4)" ::: "memory"); }
    else             { asm volatile("s_waitcnt vmcnt(0)" ::: "memory"); }
    __builtin_amdgcn_sched_barrier(0);
    asm volatile("s_barrier" ::: "memory");
    __builtin_amdgcn_sched_barrier(0);
    if (kt + 2 < nk) STG((kt + 2) % 3, (kt + 2) << 5);

    FragU af[4], bf[4];
#pragma unroll
    for (int i = 0; i < 4; ++i) {
      int rowa = wr * 64 + i * 16 + l15;
      int swa = g ^ ((rowa >> 1) & 3);
      af[i].v = *(const bf16x8*)(&lA[s][rowa * 32 + swa * 8]);
      int rowb = wc * 64 + i * 16 + l15;
      int swb = g ^ ((rowb >> 1) & 3);
      bf[i].v = *(const bf16x8*)(&lB[s][rowb * 32 + swb * 8]);
    }
#pragma unroll
    for (int i = 0; i < 4; ++i)
#pragma unroll
      for (int j = 0; j < 4; ++j)
        acc[i][j] = MFMA(af[i].v, bf[j].v, acc[i][j]);
  }
#undef STG

#pragma unroll
  for (int i = 0; i < 4; ++i) {
#pragma unroll
    for (int r = 0; r < 4; ++r) {
      int mrow = brow + wr * 64 + i * 16 + g * 4 + r;
      if (mrow >= M) continue;
      int bidx = 0, nn = 0, tt = 0;
      if constexpr (EPI == EPI_QKV || EPI == EPI_QI) { bidx = mrow / NN; nn = mrow - bidx * NN; }
      if constexpr (EPI == EPI_KVT) { bidx = mrow / NTT; tt = mrow - bidx * NTT; }
#pragma unroll
      for (int j = 0; j < 4; ++j) {
        int col = bcol + wc * 64 + j * 16 + l15;
        float val = acc[i][j][r];
        if constexpr (EPI == EPI_XOUT) {
          ep.outf[(size_t)mrow * DD + col] = val + ep.bias[col];
        } else if constexpr (EPI == EPI_FINAL) {
          size_t o = (size_t)mrow * DD + col;
          ep.outf[o] = ep.aux[o] + ep.alphap[0] * (val + ep.bias[col]);
        } else if constexpr (EPI == EPI_QKV) {
          int which = col / DD; int within = col - which * DD;
          int h = within >> 6, dd2 = within & 63;
          size_t dstp = (((size_t)bidx * HH + h) * NN + nn) * DH + dd2;
          if (which == 0) ep.o0[dstp] = f2bf(val * 0.125f);
          else if (which == 1) ep.o1[dstp] = f2bf(val);
          else ep.o2[dstp] = f2bf(val);
        } else if constexpr (EPI == EPI_QI) {
          int h = col >> 6, dd2 = col & 63;
          ep.o0[(((size_t)bidx * HH + h) * NN + nn) * DH + dd2] = f2bf(val * 0.125f);
        } else if constexpr (EPI == EPI_KVT) {
          int kvi = col / DD; int within = col - kvi * DD;
          int h = within >> 6, dd2 = within & 63;
          size_t dstp = (((size_t)bidx * HH + h) * NTT + tt) * DH + dd2;
          if (kvi == 0) ep.o0[dstp] = f2bf(val);
          else ep.o1[dstp] = f2bf(val);
        }
      }
    }
  }
}

// =====================================================================
// 256x256 GEMM, 512 threads (8 waves = 4wr x 2wc), WAVE TILE 64x128,
// ring-2 BK=32, counted vmcnt(4) (r12, QKV only).
// Rationale: GEMM is LDS-read-BW-bound (per-CU LDS pipe ~85B/cyc vs 4
// MFMA SIMDs; 0.5 ds_read/MFMA at 64x64 wave tile => MfmaUtil ~17%).
// 64x128 wave tile: 12 reads per 32 MFMA = 0.375 read/MFMA (-25% LDS
// traffic/FLOP). acc 4x8 = 128 VGPR, ~200 total -> launch_bounds(512,2)
// keeps 2 waves/SIMD; LDS 64KB -> 2 blocks/CU = 16 waves/CU; grid 450
// blocks fully co-resident. Schedule = r10-verified ring-2 2-barrier
// counted form (4 loads/thread -> vmcnt(4)); swizzle = r1-verified 64B
// row involution; defensive asm barriers; bijective XCD remap.
// =====================================================================
template <int EPI>
__global__ __launch_bounds__(512, 2)
void gemm_big(const unsigned short* __restrict__ A, const unsigned short* __restrict__ Bt,
              int M, int K, EpiParams ep) {
  __shared__ __align__(16) unsigned short lA[2][256 * 32];
  __shared__ __align__(16) unsigned short lB[2][256 * 32];
  const int nbx = gridDim.x, nwg = gridDim.x * gridDim.y;
  int flat = blockIdx.y * nbx + blockIdx.x;
  {
    int q = nwg >> 3, r = nwg & 7;
    int xcd = flat & 7, i = flat >> 3;
    flat = (xcd < r ? xcd * (q + 1) : r * (q + 1) + (xcd - r) * q) + i;
  }
  const int brow = (flat / nbx) * 256, bcol = (flat % nbx) * 256;
  const int t = threadIdx.x, wave = t >> 6, lane = t & 63, g = lane >> 4, l15 = lane & 15;
  const int wr = wave >> 1, wc = wave & 1;

  // ---- staging precompute: 2 A-granules + 2 B-granules per thread ----
  int dsto[2];
  const unsigned short *pA[2], *pB[2];
#pragma unroll
  for (int c = 0; c < 2; ++c) {
    int sb = (t + c * 512) * 8;        // element slot in 256x32 (linear dest)
    int row = sb >> 5;                 // 0..255
    int gl = (sb >> 3) & 3;
    int swz = gl ^ ((row >> 1) & 3);
    int ra = brow + row; if (ra > M - 1) ra = M - 1;
    dsto[c] = sb;
    pA[c] = A + (size_t)ra * K + swz * 8;
    pB[c] = Bt + (size_t)(bcol + row) * K + swz * 8;
  }

#define STG(bufi, k0) do { \
    gld_lds16(pA[0] + (k0), &lA[bufi][dsto[0]]); \
    gld_lds16(pB[0] + (k0), &lB[bufi][dsto[0]]); \
    gld_lds16(pA[1] + (k0), &lA[bufi][dsto[1]]); \
    gld_lds16(pB[1] + (k0), &lB[bufi][dsto[1]]); \
    __builtin_amdgcn_sched_barrier(0); } while (0)

  f32x4 acc[4][8];
#pragma unroll
  for (int i = 0; i < 4; ++i)
#pragma unroll
    for (int j = 0; j < 8; ++j) acc[i][j] = {0.f, 0.f, 0.f, 0.f};

  const int nk = K >> 5;
  STG(0, 0);
  int buf = 0;
  for (int kt = 0; kt < nk; ++kt) {
    if (kt + 1 < nk) {
      STG(buf ^ 1, (kt + 1) << 5);
      asm volatile("s_waitcnt vmcnt(4)" ::: "memory");   // retire exactly tile kt
    } else {
      asm volatile("s_waitcnt vmcnt(0)" ::: "memory");
    }
    __builtin_amdgcn_sched_barrier(0);
    asm volatile("s_barrier" ::: "memory");
    __builtin_amdgcn_sched_barrier(0);

    FragU af[4], bf[8];
#pragma unroll
    for (int i = 0; i < 4; ++i) {
      int rowa = wr * 64 + i * 16 + l15;
      int swa = g ^ ((rowa >> 1) & 3);
      af[i].v = *(const bf16x8*)(&lA[buf][rowa * 32 + swa * 8]);
    }
#pragma unroll
    for (int j = 0; j < 8; ++j) {
      int rowb = wc * 128 + j * 16 + l15;
      int swb = g ^ ((rowb >> 1) & 3);
      bf[j].v = *(const bf16x8*)(&lB[buf][rowb * 32 + swb * 8]);
    }
#pragma unroll
    for (int i = 0; i < 4; ++i)
#pragma unroll
      for (int j = 0; j < 8; ++j)
        acc[i][j] = MFMA(af[i].v, bf[j].v, acc[i][j]);

    asm volatile("s_waitcnt lgkmcnt(0)" ::: "memory");
    __builtin_amdgcn_sched_barrier(0);
    asm volatile("s_barrier" ::: "memory");
    __builtin_amdgcn_sched_barrier(0);
    buf ^= 1;
  }
#undef STG

#pragma unroll
  for (int i = 0; i < 4; ++i) {
#pragma unroll
    for (int r = 0; r < 4; ++r) {
      int mrow = brow + wr * 64 + i * 16 + g * 4 + r;
      if (mrow >= M) continue;
      int bidx = 0, nn = 0;
      if constexpr (EPI == EPI_QKV) { bidx = mrow / NN; nn = mrow - bidx * NN; }
#pragma unroll
      for (int j = 0; j < 8; ++j) {
        int col = bcol + wc * 128 + j * 16 + l15;
        float val = acc[i][j][r];
        if constexpr (EPI == EPI_QKV) {
          int which = col / DD; int within = col - which * DD;
          int h = within >> 6, dd2 = within & 63;
          size_t dstp = (((size_t)bidx * HH + h) * NN + nn) * DH + dd2;
          if (which == 0) ep.o0[dstp] = f2bf(val * 0.125f);
          else if (which == 1) ep.o1[dstp] = f2bf(val);
          else ep.o2[dstp] = f2bf(val);
        }
      }
    }
  }
}

// =====================================================================
// merged self-attention (r7-verified). blocks [0,768): frame; [768,864): CLS.
// =====================================================================
__global__ __launch_bounds__(256)
void attn_all(const unsigned short* __restrict__ qg, const unsigned short* __restrict__ kg,
              const unsigned short* __restrict__ vg, unsigned short* __restrict__ outg) {
  __shared__ __align__(16) char smem[224 * 64 * 2 + 64 * 232 * 2];
  const int t = threadIdx.x, lane = t & 63, g = lane >> 4, l15 = lane & 15;
  const int wave = t >> 6;

  if (blockIdx.x < 768) {
    unsigned short* lK = (unsigned short*)smem;                  // [224][64], granule ^= key&7
    unsigned short* lV = (unsigned short*)(smem + 224 * 64 * 2); // [64][232] transposed
    const int bid = blockIdx.x, bh = bid >> 3, fi = bid & 7;
    const int b = bh / HH, h = bh - b * HH;
    const size_t base = (size_t)bh * NN * DH;

#pragma unroll
    for (int c = 0; c < 7; ++c) {
      int gI = t + 256 * c;
      int elem = gI * 8, row = elem >> 6, gl = (elem >> 3) & 7;
      int srcg = gl ^ (row & 7);
      int rr = row < 197 ? row : 196;
      int nrow = (rr == 0) ? 0 : (fi * NFR + rr);
      gld_lds16(kg + base + (size_t)nrow * DH + srcg * 8, &lK[elem]);
    }
    {
      float4 vreg[7]; int vkey[7], ve[7];
#pragma unroll
      for (int c = 0; c < 7; ++c) {
        int gI = t + 256 * c;
        if (gI < 1576) {
          int key = gI >> 3, e = gI & 7;
          int nrow = (key == 0) ? 0 : (fi * NFR + key);
          vreg[c] = *(const float4*)(vg + base + (size_t)nrow * DH + e * 8);
          vkey[c] = key; ve[c] = e;
        }
      }
#pragma unroll
      for (int c = 0; c < 7; ++c) {
        int gI = t + 256 * c;
        if (gI < 1576) {
          const unsigned short* u = (const unsigned short*)&vreg[c];
          int d0 = ve[c] * 8, key = vkey[c];
#pragma unroll
          for (int z = 0; z < 8; ++z) lV[(d0 + z) * 232 + key] = u[z];
        }
      }
      for (int idx = t; idx < 27 * 64; idx += 256) {
        int key = 197 + (idx >> 6), dd = idx & 63;
        lV[dd * 232 + key] = 0;
      }
    }
    __syncthreads();

    for (int qt = wave; qt < 13; qt += 4) {
      int qr = qt * 16 + l15; if (qr > 195) qr = 195;
      const unsigned short* qp = qg + base + (size_t)(1 + fi * NFR + qr) * DH + g * 8;
      bf16x8 bq0 = *(const bf16x8*)(qp);
      bf16x8 bq1 = *(const bf16x8*)(qp + 32);
      f32x4 s[13];
#pragma unroll
      for (int kt2 = 0; kt2 < 13; ++kt2) {
        int krow = kt2 * 16 + l15;
        int rb = krow * 64;
        int sw0 = (g ^ (krow & 7)) * 8;
        int sw1 = ((4 + g) ^ (krow & 7)) * 8;
        f32x4 a = {0.f, 0.f, 0.f, 0.f};
        a = MFMA(*(const bf16x8*)(&lK[rb + sw0]), bq0, a);
        a = MFMA(*(const bf16x8*)(&lK[rb + sw1]), bq1, a);
        s[kt2] = a;
      }
      float m = -1e30f;
#pragma unroll
      for (int kt2 = 0; kt2 < 13; ++kt2)
#pragma unroll
        for (int r = 0; r < 4; ++r) {
          int key = kt2 * 16 + g * 4 + r;
          if (key >= 197) s[kt2][r] = -1e30f;
          m = fmaxf(m, s[kt2][r]);
        }
      m = fmaxf(m, __shfl_xor(m, 16));
      m = fmaxf(m, __shfl_xor(m, 32));
      float sum = 0.f;
#pragma unroll
      for (int kt2 = 0; kt2 < 13; ++kt2)
#pragma unroll
        for (int r = 0; r < 4; ++r) { float p = __expf(s[kt2][r] - m); s[kt2][r] = p; sum += p; }
      sum += __shfl_xor(sum, 16);
      sum += __shfl_xor(sum, 32);
      float inv = 1.f / sum;
#pragma unroll
      for (int kt2 = 0; kt2 < 13; ++kt2)
#pragma unroll
        for (int r = 0; r < 4; ++r) s[kt2][r] *= inv;
      unsigned int pk2[13][2];
#pragma unroll
      for (int c2 = 0; c2 < 13; ++c2) {
        pk2[c2][0] = cvt_pk_bf16(s[c2][0], s[c2][1]);
        pk2[c2][1] = cvt_pk_bf16(s[c2][2], s[c2][3]);
      }
      f32x4 o[4];
#pragma unroll
      for (int dt = 0; dt < 4; ++dt) o[dt] = {0.f, 0.f, 0.f, 0.f};
#pragma unroll
      for (int K32 = 0; K32 < 7; ++K32) {
        FragU af;
        unsigned int* aw = (unsigned int*)&af;
#pragma unroll
        for (int w = 0; w < 4; ++w) {
          int srcl = l15 + 16 * ((((lane >> 4) & 1) * 8 + 2 * w) >> 2);
          int v0 = __shfl((int)pk2[2 * K32][w & 1], srcl, 64);
          int v1 = (2 * K32 + 1 < 13) ? __shfl((int)pk2[2 * K32 + 1][w & 1], srcl, 64) : 0;
          aw[w] = (unsigned int)((g < 2) ? v0 : v1);
        }
#pragma unroll
        for (int dt = 0; dt < 4; ++dt) {
          const bf16x8 bv = *(const bf16x8*)(&lV[(dt * 16 + l15) * 232 + K32 * 32 + g * 8]);
          o[dt] = MFMA(af.v, bv, o[dt]);
        }
      }
#pragma unroll
      for (int dt = 0; dt < 4; ++dt)
#pragma unroll
        for (int r = 0; r < 4; ++r) {
          int qrow = qt * 16 + g * 4 + r;
          if (qrow < 196) {
            size_t nrow = 1 + (size_t)fi * NFR + qrow;
            outg[((size_t)b * NN + nrow) * DD + h * DH + dt * 16 + l15] = f2bf(o[dt][r]);
          }
        }
    }
  } else {
    float* q0 = (float*)smem;
    float* sc = (float*)(smem + 256);
    float* red = (float*)(smem + 256 + NN * 4);
    float* opart2 = (float*)(smem + 256 + NN * 4 + 1024);
    const int bh = blockIdx.x - 768, b = bh / HH, h = bh - b * HH;
    const size_t base = (size_t)bh * NN * DH;
    if (t < 64) q0[t] = bf2f(qg[base + t]);
    __syncthreads();
    for (int j = t; j < NN; j += 256) {
      const unsigned short* kr = kg + base + (size_t)j * DH;
      float s = 0.f;
#pragma unroll
      for (int dd = 0; dd < 64; dd += 8) {
        float4 raw = *(const float4*)(kr + dd);
        const unsigned short* pu = (const unsigned short*)&raw;
#pragma unroll
        for (int z = 0; z < 8; ++z) s += q0[dd + z] * bf2f(pu[z]);
      }
      sc[j] = s;
    }
    __syncthreads();
    float lm = -1e30f;
    for (int j = t; j < NN; j += 256) lm = fmaxf(lm, sc[j]);
    red[t] = lm; __syncthreads();
    for (int off = 128; off > 0; off >>= 1) { if (t < off) red[t] = fmaxf(red[t], red[t + off]); __syncthreads(); }
    float m = red[0];
    __syncthreads();
    float ls = 0.f;
    for (int j = t; j < NN; j += 256) { float p = __expf(sc[j] - m); sc[j] = p; ls += p; }
    __syncthreads();
    red[t] = ls; __syncthreads();
    for (int off = 128; off > 0; off >>= 1) { if (t < off) red[t] += red[t + off]; __syncthreads(); }
    float invS = 1.f / red[0];
    int jg = t >> 3, db = t & 7;
    float o8[8];
#pragma unroll
    for (int z = 0; z < 8; ++z) o8[z] = 0.f;
    for (int j = jg; j < NN; j += 32) {
      float sj = sc[j];
      float4 raw = *(const float4*)(vg + base + (size_t)j * DH + db * 8);
      const unsigned short* pu = (const unsigned short*)&raw;
#pragma unroll
      for (int z = 0; z < 8; ++z) o8[z] += sj * bf2f(pu[z]);
    }
#pragma unroll
    for (int z = 0; z < 8; ++z) opart2[jg * 66 + db * 8 + z] = o8[z];
    __syncthreads();
    if (t < 64) {
      float r = 0.f;
      for (int p2 = 0; p2 < 32; ++p2) r += opart2[p2 * 66 + t];
      outg[((size_t)b * NN) * DD + h * DH + t] = f2bf(r * invS);
    }
  }
}

// ---------------- i2t cross attention (r7-verified) ----------------
__global__ __launch_bounds__(256)
void i2t_attn(const unsigned short* __restrict__ qg, const unsigned short* __restrict__ ktg,
              const unsigned short* __restrict__ vtg, const float* __restrict__ mask,
              unsigned short* __restrict__ outg) {
  __shared__ __align__(16) unsigned short lK[80 * 64];
  __shared__ __align__(16) unsigned short lV[64 * 104];
  const int bid = blockIdx.x;
  const int bh = bid % 96, chunk = bid / 96;
  const int b = bh / HH, h = bh - b * HH;
  const int t = threadIdx.x, wave = t >> 6, lane = t & 63, g = lane >> 4, l15 = lane & 15;
  const size_t kvbase = (size_t)bh * NTT * DH;
#pragma unroll
  for (int c = 0; c < 3; ++c) {
    int gI = t + 256 * c;
    if (gI < 640) {
      int elem = gI * 8, row = elem >> 6, gl = (elem >> 3) & 7;
      int srcg = gl ^ (row & 7);
      int rr = row < NTT ? row : NTT - 1;
      gld_lds16(ktg + kvbase + (size_t)rr * DH + srcg * 8, &lK[elem]);
    }
  }
  {
    float4 vreg[3]; int vkey[3], ve[3];
#pragma unroll
    for (int c = 0; c < 3; ++c) {
      int gI = t + 256 * c;
      if (gI < 616) {
        int key = gI >> 3, e = gI & 7;
        vreg[c] = *(const float4*)(vtg + kvbase + (size_t)key * DH + e * 8);
        vkey[c] = key; ve[c] = e;
      }
    }
#pragma unroll
    for (int c = 0; c < 3; ++c) {
      int gI = t + 256 * c;
      if (gI < 616) {
        const unsigned short* u = (const unsigned short*)&vreg[c];
        int d0 = ve[c] * 8, key = vkey[c];
#pragma unroll
        for (int z = 0; z < 8; ++z) lV[(d0 + z) * 104 + key] = u[z];
      }
    }
    for (int idx = t; idx < 27 * 64; idx += 256) {
      int key = NTT + (idx >> 6), dd = idx & 63;
      lV[dd * 104 + key] = 0;
    }
  }
  __syncthreads();
  const size_t qbase = (size_t)bh * NN * DH;
#pragma unroll
  for (int i4 = 0; i4 < 4; ++i4) {
    int qt = chunk * 16 + i4 * 4 + wave;
    if (qt >= 99) continue;
    int qr = qt * 16 + l15; if (qr > NN - 1) qr = NN - 1;
    const unsigned short* qp = qg + qbase + (size_t)qr * DH + g * 8;
    bf16x8 bq0 = *(const bf16x8*)(qp);
    bf16x8 bq1 = *(const bf16x8*)(qp + 32);
    f32x4 s[5];
#pragma unroll
    for (int kt2 = 0; kt2 < 5; ++kt2) {
      int krow = kt2 * 16 + l15;
      int rb = krow * 64;
      int sw0 = (g ^ (krow & 7)) * 8;
      int sw1 = ((4 + g) ^ (krow & 7)) * 8;
      f32x4 a = {0.f, 0.f, 0.f, 0.f};
      a = MFMA(*(const bf16x8*)(&lK[rb + sw0]), bq0, a);
      a = MFMA(*(const bf16x8*)(&lK[rb + sw1]), bq1, a);
      s[kt2] = a;
    }
    float m = -1e30f;
#pragma unroll
    for (int kt2 = 0; kt2 < 5; ++kt2)
#pragma unroll
      for (int r = 0; r < 4; ++r) {
        int key = kt2 * 16 + g * 4 + r;
        if (key < NTT) s[kt2][r] += mask[b * NTT + key];
        else s[kt2][r] = -1e30f;
        m = fmaxf(m, s[kt2][r]);
      }
    m = fmaxf(m, __shfl_xor(m, 16));
    m = fmaxf(m, __shfl_xor(m, 32));
    float sum = 0.f;
#pragma unroll
    for (int kt2 = 0; kt2 < 5; ++kt2)
#pragma unroll
      for (int r = 0; r < 4; ++r) { float p = __expf(s[kt2][r] - m); s[kt2][r] = p; sum += p; }
    sum += __shfl_xor(sum, 16);
    sum += __shfl_xor(sum, 32);
    float inv = 1.f / sum;
#pragma unroll
    for (int kt2 = 0; kt2 < 5; ++kt2)
#pragma unroll
      for (int r = 0; r < 4; ++r) s[kt2][r] *= inv;
    unsigned int pk2[5][2];
#pragma unroll
    for (int c2 = 0; c2 < 5; ++c2) {
      pk2[c2][0] = cvt_pk_bf16(s[c2][0], s[c2][1]);
      pk2[c2][1] = cvt_pk_bf16(s[c2][2], s[c2][3]);
    }
    f32x4 o[4];
#pragma unroll
    for (int dt = 0; dt < 4; ++dt) o[dt] = {0.f, 0.f, 0.f, 0.f};
#pragma unroll
    for (int K32 = 0; K32 < 3; ++K32) {
      FragU af;
      unsigned int* aw = (unsigned int*)&af;
#pragma unroll
      for (int w = 0; w < 4; ++w) {
        int srcl = l15 + 16 * ((((lane >> 4) & 1) * 8 + 2 * w) >> 2);
        int v0 = __shfl((int)pk2[2 * K32][w & 1], srcl, 64);
        int v1 = (2 * K32 + 1 < 5) ? __shfl((int)pk2[2 * K32 + 1][w & 1], srcl, 64) : 0;
        aw[w] = (unsigned int)((g < 2) ? v0 : v1);
      }
#pragma unroll
      for (int dt = 0; dt < 4; ++dt) {
        const bf16x8 bv = *(const bf16x8*)(&lV[(dt * 16 + l15) * 104 + K32 * 32 + g * 8]);
        o[dt] = MFMA(af.v, bv, o[dt]);
      }
    }
#pragma unroll
    for (int dt = 0; dt < 4; ++dt)
#pragma unroll
      for (int r = 0; r < 4; ++r) {
        int qrow = qt * 16 + g * 4 + r;
        if (qrow < NN)
          outg[((size_t)b * NN + qrow) * DD + h * DH + dt * 16 + l15] = f2bf(o[dt][r]);
      }
  }
}

// ---------------- LayerNorm: fp32 in -> bf16 out, row = 768 ----------------
__global__ __launch_bounds__(256)
void ln_kernel(const float* __restrict__ x, const float* __restrict__ gam,
               const float* __restrict__ bet, unsigned short* __restrict__ out) {
  __shared__ float red[256];
  const int row = blockIdx.x, t = threadIdx.x;
  const size_t base = (size_t)row * DD;
  float v0 = x[base + t], v1 = x[base + t + 256], v2 = x[base + t + 512];
  red[t] = v0 + v1 + v2; __syncthreads();
  for (int off = 128; off > 0; off >>= 1) { if (t < off) red[t] += red[t + off]; __syncthreads(); }
  float mu = red[0] * (1.f / 768.f);
  __syncthreads();
  float d0 = v0 - mu, d1 = v1 - mu, d2 = v2 - mu;
  red[t] = d0 * d0 + d1 * d1 + d2 * d2; __syncthreads();
  for (int off = 128; off > 0; off >>= 1) { if (t < off) red[t] += red[t + off]; __syncthreads(); }
  float rs = rsqrtf(red[0] * (1.f / 768.f) + 1e-5f);
  out[base + t] = f2bf(d0 * rs * gam[t] + bet[t]);
  out[base + t + 256] = f2bf(d1 * rs * gam[t + 256] + bet[t + 256]);
  out[base + t + 512] = f2bf(d2 * rs * gam[t + 512] + bet[t + 512]);
}

// ---------------- workspace layout ----------------
static constexpr size_t SZ_WQKVT = (size_t)2304 * 768 * 2;
static constexpr size_t SZ_W768  = (size_t)768 * 768 * 2;
static constexpr size_t SZ_WKVT  = (size_t)1536 * 512 * 2;
static constexpr size_t SZ_XB    = (size_t)MROWS * DD * 2;
static constexpr size_t SZ_YB    = (size_t)MTEXT * DT_ * 2;
static constexpr size_t SZ_KT    = (size_t)96 * NTT * DH * 2;

static constexpr size_t OFF_WQKVT = 0;
static constexpr size_t OFF_WPROJT = OFF_WQKVT + SZ_WQKVT;
static constexpr size_t OFF_WKVT = OFF_WPROJT + SZ_W768;
static constexpr size_t OFF_WQIT = OFF_WKVT + SZ_WKVT;
static constexpr size_t OFF_WPIT = OFF_WQIT + SZ_W768;
static constexpr size_t OFF_XB  = OFF_WPIT + SZ_W768;
static constexpr size_t OFF_YB  = OFF_XB + SZ_XB;
static constexpr size_t OFF_QB  = OFF_YB + SZ_YB;
static constexpr size_t OFF_KB  = OFF_QB + SZ_XB;
static constexpr size_t OFF_VB  = OFF_KB + SZ_XB;
static constexpr size_t OFF_XOUT = OFF_VB + SZ_XB;

extern "C" void kernel_launch(void* const* d_in, const int* in_sizes, int n_in,
                              void* d_out, int out_size, void* d_ws, size_t ws_size,
                              hipStream_t stream) {
  const float* x      = (const float*)d_in[0];
  const float* y      = (const float*)d_in[1];
  const float* y_mask = (const float*)d_in[2];
  const float* w_qkv  = (const float*)d_in[4];
  const float* w_proj = (const float*)d_in[5];
  const float* b_proj = (const float*)d_in[6];
  const float* w_kv   = (const float*)d_in[7];
  const float* w_qi   = (const float*)d_in[8];
  const float* w_pi   = (const float*)d_in[9];
  const float* b_pi   = (const float*)d_in[10];
  const float* alpha  = (const float*)d_in[11];
  const float* ln_g   = (const float*)d_in[12];
  const float* ln_b   = (const float*)d_in[13];
  float* out = (float*)d_out;
  char* ws = (char*)d_ws;

  us_t* wqkvT = (us_t*)(ws + OFF_WQKVT);
  us_t* wprojT = (us_t*)(ws + OFF_WPROJT);
  us_t* wkvT = (us_t*)(ws + OFF_WKVT);
  us_t* wqiT = (us_t*)(ws + OFF_WQIT);
  us_t* wpiT = (us_t*)(ws + OFF_WPIT);
  us_t* xb  = (us_t*)(ws + OFF_XB);
  us_t* yb  = (us_t*)(ws + OFF_YB);
  us_t* qb  = (us_t*)(ws + OFF_QB);
  us_t* kb  = (us_t*)(ws + OFF_KB);
  us_t* vb  = (us_t*)(ws + OFF_VB);
  float* xoutf = (float*)(ws + OFF_XOUT);
  us_t* attn_out = xb;
  us_t* lnout = qb;
  us_t* qib = kb;
  us_t* ktb = vb;
  us_t* vtb = (us_t*)(ws + OFF_VB + SZ_KT);
  us_t* i2t_out = xb;

  // 1) fused conversions + fused weight transposes
  cvt_fused<<<2048, 256, 0, stream>>>(x, xb, MROWS * DD / 4, y, yb, MTEXT * DT_ / 4);
  TJobs tj;
  tj.in[0] = w_qkv;  tj.out[0] = wqkvT;  tj.R[0] = 768; tj.C[0] = 2304;
  tj.in[1] = w_proj; tj.out[1] = wprojT; tj.R[1] = 768; tj.C[1] = 768;
  tj.in[2] = w_kv;   tj.out[2] = wkvT;   tj.R[2] = 512; tj.C[2] = 1536;
  tj.in[3] = w_qi;   tj.out[3] = wqiT;   tj.R[3] = 768; tj.C[3] = 768;
  tj.in[4] = w_pi;   tj.out[4] = wpiT;   tj.R[4] = 768; tj.C[4] = 768;
  transpose_all<<<dim3(72, 24, 5), 256, 0, stream>>>(tj);

  // 2) qkv projection (256x256, wave tile 64x128, ring-2)
  EpiParams e1{}; e1.o0 = qb; e1.o1 = kb; e1.o2 = vb;
  gemm_big<EPI_QKV><<<dim3(9, 50), 512, 0, stream>>>(xb, wqkvT, MROWS, 768, e1);

  // 3) self attention (frame + cls merged)
  attn_all<<<864, 256, 0, stream>>>(qb, kb, vb, attn_out);

  // 4) out projection + bias -> x_out (fp32)  [one-barrier ring-3]
  EpiParams e2{}; e2.outf = xoutf; e2.bias = b_proj;
  gemm_bt<EPI_XOUT><<<dim3(6, 99), 256, 0, stream>>>(attn_out, wprojT, MROWS, 768, e2);

  // 5) LN -> bf16
  ln_kernel<<<MROWS, 256, 0, stream>>>(xoutf, ln_g, ln_b, lnout);

  // 6) q_i projection (scaled)  [one-barrier ring-3]
  EpiParams e3{}; e3.o0 = qib;
  gemm_bt<EPI_QI><<<dim3(6, 99), 256, 0, stream>>>(lnout, wqiT, MROWS, 768, e3);

  // 7) text kv projection  [one-barrier ring-3]
  EpiParams e4{}; e4.o0 = ktb; e4.o1 = vtb;
  gemm_bt<EPI_KVT><<<dim3(12, 5), 256, 0, stream>>>(yb, wkvT, MTEXT, 512, e4);

  // 8) i2t cross attention
  i2t_attn<<<dim3(96 * 7), 256, 0, stream>>>(qib, ktb, vtb, y_mask, i2t_out);

  // 9) final projection + bias, fused d_out = x_out + alpha*yo  [one-barrier ring-3]
  EpiParams e5{}; e5.outf = out; e5.bias = b_pi; e5.aux = xoutf; e5.alphap = alpha;
  gemm_bt<EPI_FINAL><<<dim3(6, 99), 256, 0, stream>>>(i2t_out, wpiT, MROWS, 768, e5);
}

// Round 15
// 316.225 us; speedup vs baseline: 1.2116x; 1.2116x over previous
//
#include <hip/hip_runtime.h>

// ---------------- types & helpers ----------------
typedef __bf16 bf16x8 __attribute__((ext_vector_type(8)));
typedef float f32x4 __attribute__((ext_vector_type(4)));
typedef unsigned short us_t;

#define DEV __device__ __forceinline__

DEV float bf2f(unsigned short u) {
  union { unsigned int i; float f; } c; c.i = ((unsigned int)u) << 16; return c.f;
}
DEV unsigned short f2bf(float f) {
  union { float f; unsigned int i; } c; c.f = f;
  return (unsigned short)((c.i + 0x7FFFu + ((c.i >> 16) & 1u)) >> 16);
}
DEV unsigned int cvt_pk_bf16(float lo, float hi) {
  unsigned int r;
  asm("v_cvt_pk_bf16_f32 %0, %1, %2" : "=v"(r) : "v"(lo), "v"(hi));
  return r;
}

union FragU { bf16x8 v; unsigned short u[8]; };

DEV void gld_lds16(const void* g, void* l) {
  __builtin_amdgcn_global_load_lds((const __attribute__((address_space(1))) void*)g,
                                   (__attribute__((address_space(3))) void*)l, 16, 0, 0);
}

#define MFMA(a, b, c) __builtin_amdgcn_mfma_f32_16x16x32_bf16((a), (b), (c), 0, 0, 0)

// ---------------- problem constants ----------------
#define BB 8
#define NN 1569
#define DD 768
#define HH 12
#define DH 64
#define FF 8
#define NFR 196
#define NTT 77
#define DT_ 512
#define MROWS 12552   // B*N
#define MTEXT 616     // B*NT

// ---------------- fused prep: 5 transpose jobs (z<5) + fp32->bf16 cvt (z==5) ----------------
struct PrepJobs {
  const float* in[5];
  unsigned short* out[5];
  int R[5], C[5];
  const float* xin; unsigned short* xout; int n4x;
  const float* yin; unsigned short* yout; int n4y;
};

__global__ __launch_bounds__(256) void prep_all(PrepJobs j) {
  int z = blockIdx.z;
  if (z == 5) {
    int i = (blockIdx.y * gridDim.x + blockIdx.x) * blockDim.x + threadIdx.x;
    int stride = gridDim.x * gridDim.y * blockDim.x;
    int total = j.n4x + j.n4y;
    for (; i < total; i += stride) {
      const float4* src; ushort4* dst; int idx;
      if (i < j.n4x) { src = (const float4*)j.xin; dst = (ushort4*)j.xout; idx = i; }
      else           { src = (const float4*)j.yin; dst = (ushort4*)j.yout; idx = i - j.n4x; }
      float4 v = src[idx];
      ushort4 o;
      o.x = f2bf(v.x); o.y = f2bf(v.y); o.z = f2bf(v.z); o.w = f2bf(v.w);
      dst[idx] = o;
    }
    return;
  }
  __shared__ float tile[32][33];
  int R = j.R[z], C = j.C[z];
  int bx = blockIdx.x * 32;   // C base
  int by = blockIdx.y * 32;   // R base
  if (bx >= C || by >= R) return;
  const float* in = j.in[z];
  unsigned short* out = j.out[z];
  int tx = threadIdx.x & 31;
  int ty0 = threadIdx.x >> 5; // 0..7
  for (int dy = 0; dy < 32; dy += 8) {
    int r = by + ty0 + dy, c = bx + tx;
    tile[ty0 + dy][tx] = (r < R && c < C) ? in[(size_t)r * C + c] : 0.f;
  }
  __syncthreads();
  for (int dy = 0; dy < 32; dy += 8) {
    int orow = bx + ty0 + dy;  // C index
    int ocol = by + tx;        // R index
    if (orow < C && ocol < R) out[(size_t)orow * R + ocol] = f2bf(tile[tx][ty0 + dy]);
  }
}

// ---------------- epilogue kinds ----------------
enum { EPI_QKV = 0, EPI_XOUT = 1, EPI_QI = 2, EPI_KVT = 3, EPI_FINAL = 4 };

struct EpiParams {
  float* outf;
  unsigned short *o0, *o1, *o2;
  const float *bias, *aux, *alphap;
};

// =====================================================================
// 128x128 GEMM, ring-3 ONE-barrier pipeline (r11-verified).
// Used for XOUT/QI/FINAL (768-col) and KVT.
// =====================================================================
template <int EPI>
__global__ __launch_bounds__(256)
void gemm_bt(const unsigned short* __restrict__ A, const unsigned short* __restrict__ Bt,
             int M, int K, EpiParams ep) {
  __shared__ __align__(16) unsigned short lA[3][128 * 32];
  __shared__ __align__(16) unsigned short lB[3][128 * 32];
  const int nbx = gridDim.x, nwg = gridDim.x * gridDim.y;
  int flat = blockIdx.y * nbx + blockIdx.x;
  {
    int q = nwg >> 3, r = nwg & 7;
    int xcd = flat & 7, i = flat >> 3;
    flat = (xcd < r ? xcd * (q + 1) : r * (q + 1) + (xcd - r) * q) + i;
  }
  const int brow = (flat / nbx) * 128, bcol = (flat % nbx) * 128;
  const int t = threadIdx.x, wave = t >> 6, lane = t & 63, g = lane >> 4, l15 = lane & 15;
  const int wr = wave >> 1, wc = wave & 1;

  int dsto[2];
  const unsigned short *pA[2], *pB[2];
#pragma unroll
  for (int c = 0; c < 2; ++c) {
    int sb = wave * 1024 + c * 512;
    int slot = sb + lane * 8;
    int row = slot >> 5;
    int gl = (slot >> 3) & 3;
    int swz = gl ^ ((row >> 1) & 3);
    int ra = brow + row; if (ra > M - 1) ra = M - 1;
    dsto[c] = sb;
    pA[c] = A + (size_t)ra * K + swz * 8;
    pB[c] = Bt + (size_t)(bcol + row) * K + swz * 8;
  }

#define STG(s, k0) do { \
    gld_lds16(pA[0] + (k0), &lA[s][dsto[0]]); \
    gld_lds16(pB[0] + (k0), &lB[s][dsto[0]]); \
    gld_lds16(pA[1] + (k0), &lA[s][dsto[1]]); \
    gld_lds16(pB[1] + (k0), &lB[s][dsto[1]]); \
    __builtin_amdgcn_sched_barrier(0); } while (0)

  f32x4 acc[4][4];
#pragma unroll
  for (int i = 0; i < 4; ++i)
#pragma unroll
    for (int j = 0; j < 4; ++j) acc[i][j] = {0.f, 0.f, 0.f, 0.f};

  const int nk = K >> 5;
  STG(0, 0);
  if (nk > 1) STG(1, 32);

  for (int kt = 0; kt < nk; ++kt) {
    const int s = kt % 3;
    if (kt + 1 < nk) { asm volatile("s_waitcnt vmcnt(4)" ::: "memory"); }
    else             { asm volatile("s_waitcnt vmcnt(0)" ::: "memory"); }
    __builtin_amdgcn_sched_barrier(0);
    asm volatile("s_barrier" ::: "memory");
    __builtin_amdgcn_sched_barrier(0);
    if (kt + 2 < nk) STG((kt + 2) % 3, (kt + 2) << 5);

    FragU af[4], bf[4];
#pragma unroll
    for (int i = 0; i < 4; ++i) {
      int rowa = wr * 64 + i * 16 + l15;
      int swa = g ^ ((rowa >> 1) & 3);
      af[i].v = *(const bf16x8*)(&lA[s][rowa * 32 + swa * 8]);
      int rowb = wc * 64 + i * 16 + l15;
      int swb = g ^ ((rowb >> 1) & 3);
      bf[i].v = *(const bf16x8*)(&lB[s][rowb * 32 + swb * 8]);
    }
#pragma unroll
    for (int i = 0; i < 4; ++i)
#pragma unroll
      for (int j = 0; j < 4; ++j)
        acc[i][j] = MFMA(af[i].v, bf[j].v, acc[i][j]);
  }
#undef STG

#pragma unroll
  for (int i = 0; i < 4; ++i) {
#pragma unroll
    for (int r = 0; r < 4; ++r) {
      int mrow = brow + wr * 64 + i * 16 + g * 4 + r;
      if (mrow >= M) continue;
      int bidx = 0, nn = 0, tt = 0;
      if constexpr (EPI == EPI_QI) { bidx = mrow / NN; nn = mrow - bidx * NN; }
      if constexpr (EPI == EPI_KVT) { bidx = mrow / NTT; tt = mrow - bidx * NTT; }
#pragma unroll
      for (int j = 0; j < 4; ++j) {
        int col = bcol + wc * 64 + j * 16 + l15;
        float val = acc[i][j][r];
        if constexpr (EPI == EPI_XOUT) {
          ep.outf[(size_t)mrow * DD + col] = val + ep.bias[col];
        } else if constexpr (EPI == EPI_FINAL) {
          size_t o = (size_t)mrow * DD + col;
          ep.outf[o] = ep.aux[o] + ep.alphap[0] * (val + ep.bias[col]);
        } else if constexpr (EPI == EPI_QI) {
          int h = col >> 6, dd2 = col & 63;
          ep.o0[(((size_t)bidx * HH + h) * NN + nn) * DH + dd2] = f2bf(val * 0.125f);
        } else if constexpr (EPI == EPI_KVT) {
          int kvi = col / DD; int within = col - kvi * DD;
          int h = within >> 6, dd2 = within & 63;
          size_t dstp = (((size_t)bidx * HH + h) * NTT + tt) * DH + dd2;
          if (kvi == 0) ep.o0[dstp] = f2bf(val);
          else ep.o1[dstp] = f2bf(val);
        }
      }
    }
  }
}

// =====================================================================
// QKV GEMM: 128x256 tile, 512 threads (8 waves = 2wr x 4wc), ring-2
// BK=32, counted vmcnt(3) (r10/r11-verified, best measured QKV: ~111us).
// =====================================================================
__global__ __launch_bounds__(512)
void gemm_w(const unsigned short* __restrict__ A, const unsigned short* __restrict__ Bt,
            int M, int K, EpiParams ep) {
  __shared__ __align__(16) unsigned short lA[2][128 * 32];
  __shared__ __align__(16) unsigned short lB[2][256 * 32];
  const int nbx = gridDim.x, nwg = gridDim.x * gridDim.y;
  int flat = blockIdx.y * nbx + blockIdx.x;
  {
    int q = nwg >> 3, r = nwg & 7;
    int xcd = flat & 7, i = flat >> 3;
    flat = (xcd < r ? xcd * (q + 1) : r * (q + 1) + (xcd - r) * q) + i;
  }
  const int brow = (flat / nbx) * 128, bcol = (flat % nbx) * 256;
  const int t = threadIdx.x, wave = t >> 6, lane = t & 63, g = lane >> 4, l15 = lane & 15;
  const int wr = wave >> 2, wc = wave & 3;

  int dstA; const unsigned short* pA;
  {
    int sb = t * 8;
    int row = sb >> 5;
    int gl = (sb >> 3) & 3;
    int swz = gl ^ ((row >> 1) & 3);
    int ra = brow + row; if (ra > M - 1) ra = M - 1;
    dstA = sb;
    pA = A + (size_t)ra * K + swz * 8;
  }
  int dstB[2]; const unsigned short* pB[2];
#pragma unroll
  for (int c = 0; c < 2; ++c) {
    int sb = (t + c * 512) * 8;
    int row = sb >> 5;
    int gl = (sb >> 3) & 3;
    int swz = gl ^ ((row >> 1) & 3);
    dstB[c] = sb;
    pB[c] = Bt + (size_t)(bcol + row) * K + swz * 8;
  }

#define STG(bufi, k0) do { \
    gld_lds16(pA + (k0), &lA[bufi][dstA]); \
    gld_lds16(pB[0] + (k0), &lB[bufi][dstB[0]]); \
    gld_lds16(pB[1] + (k0), &lB[bufi][dstB[1]]); \
    __builtin_amdgcn_sched_barrier(0); } while (0)

  f32x4 acc[4][4];
#pragma unroll
  for (int i = 0; i < 4; ++i)
#pragma unroll
    for (int j = 0; j < 4; ++j) acc[i][j] = {0.f, 0.f, 0.f, 0.f};

  const int nk = K >> 5;
  STG(0, 0);
  int buf = 0;
  for (int kt = 0; kt < nk; ++kt) {
    if (kt + 1 < nk) {
      STG(buf ^ 1, (kt + 1) << 5);
      asm volatile("s_waitcnt vmcnt(3)" ::: "memory");
    } else {
      asm volatile("s_waitcnt vmcnt(0)" ::: "memory");
    }
    __builtin_amdgcn_sched_barrier(0);
    asm volatile("s_barrier" ::: "memory");
    __builtin_amdgcn_sched_barrier(0);

    FragU af[4], bf[4];
#pragma unroll
    for (int i = 0; i < 4; ++i) {
      int rowa = wr * 64 + i * 16 + l15;
      int swa = g ^ ((rowa >> 1) & 3);
      af[i].v = *(const bf16x8*)(&lA[buf][rowa * 32 + swa * 8]);
      int rowb = wc * 64 + i * 16 + l15;
      int swb = g ^ ((rowb >> 1) & 3);
      bf[i].v = *(const bf16x8*)(&lB[buf][rowb * 32 + swb * 8]);
    }
#pragma unroll
    for (int i = 0; i < 4; ++i)
#pragma unroll
      for (int j = 0; j < 4; ++j)
        acc[i][j] = MFMA(af[i].v, bf[j].v, acc[i][j]);

    asm volatile("s_waitcnt lgkmcnt(0)" ::: "memory");
    __builtin_amdgcn_sched_barrier(0);
    asm volatile("s_barrier" ::: "memory");
    __builtin_amdgcn_sched_barrier(0);
    buf ^= 1;
  }
#undef STG

#pragma unroll
  for (int i = 0; i < 4; ++i) {
#pragma unroll
    for (int r = 0; r < 4; ++r) {
      int mrow = brow + wr * 64 + i * 16 + g * 4 + r;
      if (mrow >= M) continue;
      int bidx = mrow / NN, nn = mrow - bidx * NN;
#pragma unroll
      for (int j = 0; j < 4; ++j) {
        int col = bcol + wc * 64 + j * 16 + l15;
        float val = acc[i][j][r];
        int which = col / DD; int within = col - which * DD;
        int h = within >> 6, dd2 = within & 63;
        size_t dstp = (((size_t)bidx * HH + h) * NN + nn) * DH + dd2;
        if (which == 0) ep.o0[dstp] = f2bf(val * 0.125f);
        else if (which == 1) ep.o1[dstp] = f2bf(val);
        else ep.o2[dstp] = f2bf(val);
      }
    }
  }
}

// =====================================================================
// merged self-attention (r7-verified). blocks [0,768): frame; [768,864): CLS.
// =====================================================================
__global__ __launch_bounds__(256)
void attn_all(const unsigned short* __restrict__ qg, const unsigned short* __restrict__ kg,
              const unsigned short* __restrict__ vg, unsigned short* __restrict__ outg) {
  __shared__ __align__(16) char smem[224 * 64 * 2 + 64 * 232 * 2];
  const int t = threadIdx.x, lane = t & 63, g = lane >> 4, l15 = lane & 15;
  const int wave = t >> 6;

  if (blockIdx.x < 768) {
    unsigned short* lK = (unsigned short*)smem;                  // [224][64], granule ^= key&7
    unsigned short* lV = (unsigned short*)(smem + 224 * 64 * 2); // [64][232] transposed
    const int bid = blockIdx.x, bh = bid >> 3, fi = bid & 7;
    const int b = bh / HH, h = bh - b * HH;
    const size_t base = (size_t)bh * NN * DH;

#pragma unroll
    for (int c = 0; c < 7; ++c) {
      int gI = t + 256 * c;
      int elem = gI * 8, row = elem >> 6, gl = (elem >> 3) & 7;
      int srcg = gl ^ (row & 7);
      int rr = row < 197 ? row : 196;
      int nrow = (rr == 0) ? 0 : (fi * NFR + rr);
      gld_lds16(kg + base + (size_t)nrow * DH + srcg * 8, &lK[elem]);
    }
    {
      float4 vreg[7]; int vkey[7], ve[7];
#pragma unroll
      for (int c = 0; c < 7; ++c) {
        int gI = t + 256 * c;
        if (gI < 1576) {
          int key = gI >> 3, e = gI & 7;
          int nrow = (key == 0) ? 0 : (fi * NFR + key);
          vreg[c] = *(const float4*)(vg + base + (size_t)nrow * DH + e * 8);
          vkey[c] = key; ve[c] = e;
        }
      }
#pragma unroll
      for (int c = 0; c < 7; ++c) {
        int gI = t + 256 * c;
        if (gI < 1576) {
          const unsigned short* u = (const unsigned short*)&vreg[c];
          int d0 = ve[c] * 8, key = vkey[c];
#pragma unroll
          for (int z = 0; z < 8; ++z) lV[(d0 + z) * 232 + key] = u[z];
        }
      }
      for (int idx = t; idx < 27 * 64; idx += 256) {
        int key = 197 + (idx >> 6), dd = idx & 63;
        lV[dd * 232 + key] = 0;
      }
    }
    __syncthreads();

    for (int qt = wave; qt < 13; qt += 4) {
      int qr = qt * 16 + l15; if (qr > 195) qr = 195;
      const unsigned short* qp = qg + base + (size_t)(1 + fi * NFR + qr) * DH + g * 8;
      bf16x8 bq0 = *(const bf16x8*)(qp);
      bf16x8 bq1 = *(const bf16x8*)(qp + 32);
      f32x4 s[13];
#pragma unroll
      for (int kt2 = 0; kt2 < 13; ++kt2) {
        int krow = kt2 * 16 + l15;
        int rb = krow * 64;
        int sw0 = (g ^ (krow & 7)) * 8;
        int sw1 = ((4 + g) ^ (krow & 7)) * 8;
        f32x4 a = {0.f, 0.f, 0.f, 0.f};
        a = MFMA(*(const bf16x8*)(&lK[rb + sw0]), bq0, a);
        a = MFMA(*(const bf16x8*)(&lK[rb + sw1]), bq1, a);
        s[kt2] = a;
      }
      float m = -1e30f;
#pragma unroll
      for (int kt2 = 0; kt2 < 13; ++kt2)
#pragma unroll
        for (int r = 0; r < 4; ++r) {
          int key = kt2 * 16 + g * 4 + r;
          if (key >= 197) s[kt2][r] = -1e30f;
          m = fmaxf(m, s[kt2][r]);
        }
      m = fmaxf(m, __shfl_xor(m, 16));
      m = fmaxf(m, __shfl_xor(m, 32));
      float sum = 0.f;
#pragma unroll
      for (int kt2 = 0; kt2 < 13; ++kt2)
#pragma unroll
        for (int r = 0; r < 4; ++r) { float p = __expf(s[kt2][r] - m); s[kt2][r] = p; sum += p; }
      sum += __shfl_xor(sum, 16);
      sum += __shfl_xor(sum, 32);
      float inv = 1.f / sum;
#pragma unroll
      for (int kt2 = 0; kt2 < 13; ++kt2)
#pragma unroll
        for (int r = 0; r < 4; ++r) s[kt2][r] *= inv;
      unsigned int pk2[13][2];
#pragma unroll
      for (int c2 = 0; c2 < 13; ++c2) {
        pk2[c2][0] = cvt_pk_bf16(s[c2][0], s[c2][1]);
        pk2[c2][1] = cvt_pk_bf16(s[c2][2], s[c2][3]);
      }
      f32x4 o[4];
#pragma unroll
      for (int dt = 0; dt < 4; ++dt) o[dt] = {0.f, 0.f, 0.f, 0.f};
#pragma unroll
      for (int K32 = 0; K32 < 7; ++K32) {
        FragU af;
        unsigned int* aw = (unsigned int*)&af;
#pragma unroll
        for (int w = 0; w < 4; ++w) {
          int srcl = l15 + 16 * ((((lane >> 4) & 1) * 8 + 2 * w) >> 2);
          int v0 = __shfl((int)pk2[2 * K32][w & 1], srcl, 64);
          int v1 = (2 * K32 + 1 < 13) ? __shfl((int)pk2[2 * K32 + 1][w & 1], srcl, 64) : 0;
          aw[w] = (unsigned int)((g < 2) ? v0 : v1);
        }
#pragma unroll
        for (int dt = 0; dt < 4; ++dt) {
          const bf16x8 bv = *(const bf16x8*)(&lV[(dt * 16 + l15) * 232 + K32 * 32 + g * 8]);
          o[dt] = MFMA(af.v, bv, o[dt]);
        }
      }
#pragma unroll
      for (int dt = 0; dt < 4; ++dt)
#pragma unroll
        for (int r = 0; r < 4; ++r) {
          int qrow = qt * 16 + g * 4 + r;
          if (qrow < 196) {
            size_t nrow = 1 + (size_t)fi * NFR + qrow;
            outg[((size_t)b * NN + nrow) * DD + h * DH + dt * 16 + l15] = f2bf(o[dt][r]);
          }
        }
    }
  } else {
    float* q0 = (float*)smem;
    float* sc = (float*)(smem + 256);
    float* red = (float*)(smem + 256 + NN * 4);
    float* opart2 = (float*)(smem + 256 + NN * 4 + 1024);
    const int bh = blockIdx.x - 768, b = bh / HH, h = bh - b * HH;
    const size_t base = (size_t)bh * NN * DH;
    if (t < 64) q0[t] = bf2f(qg[base + t]);
    __syncthreads();
    for (int j = t; j < NN; j += 256) {
      const unsigned short* kr = kg + base + (size_t)j * DH;
      float s = 0.f;
#pragma unroll
      for (int dd = 0; dd < 64; dd += 8) {
        float4 raw = *(const float4*)(kr + dd);
        const unsigned short* pu = (const unsigned short*)&raw;
#pragma unroll
        for (int z = 0; z < 8; ++z) s += q0[dd + z] * bf2f(pu[z]);
      }
      sc[j] = s;
    }
    __syncthreads();
    float lm = -1e30f;
    for (int j = t; j < NN; j += 256) lm = fmaxf(lm, sc[j]);
    red[t] = lm; __syncthreads();
    for (int off = 128; off > 0; off >>= 1) { if (t < off) red[t] = fmaxf(red[t], red[t + off]); __syncthreads(); }
    float m = red[0];
    __syncthreads();
    float ls = 0.f;
    for (int j = t; j < NN; j += 256) { float p = __expf(sc[j] - m); sc[j] = p; ls += p; }
    __syncthreads();
    red[t] = ls; __syncthreads();
    for (int off = 128; off > 0; off >>= 1) { if (t < off) red[t] += red[t + off]; __syncthreads(); }
    float invS = 1.f / red[0];
    int jg = t >> 3, db = t & 7;
    float o8[8];
#pragma unroll
    for (int z = 0; z < 8; ++z) o8[z] = 0.f;
    for (int j = jg; j < NN; j += 32) {
      float sj = sc[j];
      float4 raw = *(const float4*)(vg + base + (size_t)j * DH + db * 8);
      const unsigned short* pu = (const unsigned short*)&raw;
#pragma unroll
      for (int z = 0; z < 8; ++z) o8[z] += sj * bf2f(pu[z]);
    }
#pragma unroll
    for (int z = 0; z < 8; ++z) opart2[jg * 66 + db * 8 + z] = o8[z];
    __syncthreads();
    if (t < 64) {
      float r = 0.f;
      for (int p2 = 0; p2 < 32; ++p2) r += opart2[p2 * 66 + t];
      outg[((size_t)b * NN) * DD + h * DH + t] = f2bf(r * invS);
    }
  }
}

// ---------------- i2t cross attention (r7-verified) ----------------
__global__ __launch_bounds__(256)
void i2t_attn(const unsigned short* __restrict__ qg, const unsigned short* __restrict__ ktg,
              const unsigned short* __restrict__ vtg, const float* __restrict__ mask,
              unsigned short* __restrict__ outg) {
  __shared__ __align__(16) unsigned short lK[80 * 64];
  __shared__ __align__(16) unsigned short lV[64 * 104];
  const int bid = blockIdx.x;
  const int bh = bid % 96, chunk = bid / 96;
  const int b = bh / HH, h = bh - b * HH;
  const int t = threadIdx.x, wave = t >> 6, lane = t & 63, g = lane >> 4, l15 = lane & 15;
  const size_t kvbase = (size_t)bh * NTT * DH;
#pragma unroll
  for (int c = 0; c < 3; ++c) {
    int gI = t + 256 * c;
    if (gI < 640) {
      int elem = gI * 8, row = elem >> 6, gl = (elem >> 3) & 7;
      int srcg = gl ^ (row & 7);
      int rr = row < NTT ? row : NTT - 1;
      gld_lds16(ktg + kvbase + (size_t)rr * DH + srcg * 8, &lK[elem]);
    }
  }
  {
    float4 vreg[3]; int vkey[3], ve[3];
#pragma unroll
    for (int c = 0; c < 3; ++c) {
      int gI = t + 256 * c;
      if (gI < 616) {
        int key = gI >> 3, e = gI & 7;
        vreg[c] = *(const float4*)(vtg + kvbase + (size_t)key * DH + e * 8);
        vkey[c] = key; ve[c] = e;
      }
    }
#pragma unroll
    for (int c = 0; c < 3; ++c) {
      int gI = t + 256 * c;
      if (gI < 616) {
        const unsigned short* u = (const unsigned short*)&vreg[c];
        int d0 = ve[c] * 8, key = vkey[c];
#pragma unroll
        for (int z = 0; z < 8; ++z) lV[(d0 + z) * 104 + key] = u[z];
      }
    }
    for (int idx = t; idx < 27 * 64; idx += 256) {
      int key = NTT + (idx >> 6), dd = idx & 63;
      lV[dd * 104 + key] = 0;
    }
  }
  __syncthreads();
  const size_t qbase = (size_t)bh * NN * DH;
#pragma unroll
  for (int i4 = 0; i4 < 4; ++i4) {
    int qt = chunk * 16 + i4 * 4 + wave;
    if (qt >= 99) continue;
    int qr = qt * 16 + l15; if (qr > NN - 1) qr = NN - 1;
    const unsigned short* qp = qg + qbase + (size_t)qr * DH + g * 8;
    bf16x8 bq0 = *(const bf16x8*)(qp);
    bf16x8 bq1 = *(const bf16x8*)(qp + 32);
    f32x4 s[5];
#pragma unroll
    for (int kt2 = 0; kt2 < 5; ++kt2) {
      int krow = kt2 * 16 + l15;
      int rb = krow * 64;
      int sw0 = (g ^ (krow & 7)) * 8;
      int sw1 = ((4 + g) ^ (krow & 7)) * 8;
      f32x4 a = {0.f, 0.f, 0.f, 0.f};
      a = MFMA(*(const bf16x8*)(&lK[rb + sw0]), bq0, a);
      a = MFMA(*(const bf16x8*)(&lK[rb + sw1]), bq1, a);
      s[kt2] = a;
    }
    float m = -1e30f;
#pragma unroll
    for (int kt2 = 0; kt2 < 5; ++kt2)
#pragma unroll
      for (int r = 0; r < 4; ++r) {
        int key = kt2 * 16 + g * 4 + r;
        if (key < NTT) s[kt2][r] += mask[b * NTT + key];
        else s[kt2][r] = -1e30f;
        m = fmaxf(m, s[kt2][r]);
      }
    m = fmaxf(m, __shfl_xor(m, 16));
    m = fmaxf(m, __shfl_xor(m, 32));
    float sum = 0.f;
#pragma unroll
    for (int kt2 = 0; kt2 < 5; ++kt2)
#pragma unroll
      for (int r = 0; r < 4; ++r) { float p = __expf(s[kt2][r] - m); s[kt2][r] = p; sum += p; }
    sum += __shfl_xor(sum, 16);
    sum += __shfl_xor(sum, 32);
    float inv = 1.f / sum;
#pragma unroll
    for (int kt2 = 0; kt2 < 5; ++kt2)
#pragma unroll
      for (int r = 0; r < 4; ++r) s[kt2][r] *= inv;
    unsigned int pk2[5][2];
#pragma unroll
    for (int c2 = 0; c2 < 5; ++c2) {
      pk2[c2][0] = cvt_pk_bf16(s[c2][0], s[c2][1]);
      pk2[c2][1] = cvt_pk_bf16(s[c2][2], s[c2][3]);
    }
    f32x4 o[4];
#pragma unroll
    for (int dt = 0; dt < 4; ++dt) o[dt] = {0.f, 0.f, 0.f, 0.f};
#pragma unroll
    for (int K32 = 0; K32 < 3; ++K32) {
      FragU af;
      unsigned int* aw = (unsigned int*)&af;
#pragma unroll
      for (int w = 0; w < 4; ++w) {
        int srcl = l15 + 16 * ((((lane >> 4) & 1) * 8 + 2 * w) >> 2);
        int v0 = __shfl((int)pk2[2 * K32][w & 1], srcl, 64);
        int v1 = (2 * K32 + 1 < 5) ? __shfl((int)pk2[2 * K32 + 1][w & 1], srcl, 64) : 0;
        aw[w] = (unsigned int)((g < 2) ? v0 : v1);
      }
#pragma unroll
      for (int dt = 0; dt < 4; ++dt) {
        const bf16x8 bv = *(const bf16x8*)(&lV[(dt * 16 + l15) * 104 + K32 * 32 + g * 8]);
        o[dt] = MFMA(af.v, bv, o[dt]);
      }
    }
#pragma unroll
    for (int dt = 0; dt < 4; ++dt)
#pragma unroll
      for (int r = 0; r < 4; ++r) {
        int qrow = qt * 16 + g * 4 + r;
        if (qrow < NN)
          outg[((size_t)b * NN + qrow) * DD + h * DH + dt * 16 + l15] = f2bf(o[dt][r]);
      }
  }
}

// ---------------- LayerNorm: fp32 in -> bf16 out, row = 768 ----------------
__global__ __launch_bounds__(256)
void ln_kernel(const float* __restrict__ x, const float* __restrict__ gam,
               const float* __restrict__ bet, unsigned short* __restrict__ out) {
  __shared__ float red[256];
  const int row = blockIdx.x, t = threadIdx.x;
  const size_t base = (size_t)row * DD;
  float v0 = x[base + t], v1 = x[base + t + 256], v2 = x[base + t + 512];
  red[t] = v0 + v1 + v2; __syncthreads();
  for (int off = 128; off > 0; off >>= 1) { if (t < off) red[t] += red[t + off]; __syncthreads(); }
  float mu = red[0] * (1.f / 768.f);
  __syncthreads();
  float d0 = v0 - mu, d1 = v1 - mu, d2 = v2 - mu;
  red[t] = d0 * d0 + d1 * d1 + d2 * d2; __syncthreads();
  for (int off = 128; off > 0; off >>= 1) { if (t < off) red[t] += red[t + off]; __syncthreads(); }
  float rs = rsqrtf(red[0] * (1.f / 768.f) + 1e-5f);
  out[base + t] = f2bf(d0 * rs * gam[t] + bet[t]);
  out[base + t + 256] = f2bf(d1 * rs * gam[t + 256] + bet[t + 256]);
  out[base + t + 512] = f2bf(d2 * rs * gam[t + 512] + bet[t + 512]);
}

// ---------------- workspace layout ----------------
static constexpr size_t SZ_WQKVT = (size_t)2304 * 768 * 2;
static constexpr size_t SZ_W768  = (size_t)768 * 768 * 2;
static constexpr size_t SZ_WKVT  = (size_t)1536 * 512 * 2;
static constexpr size_t SZ_XB    = (size_t)MROWS * DD * 2;
static constexpr size_t SZ_YB    = (size_t)MTEXT * DT_ * 2;
static constexpr size_t SZ_KT    = (size_t)96 * NTT * DH * 2;

static constexpr size_t OFF_WQKVT = 0;
static constexpr size_t OFF_WPROJT = OFF_WQKVT + SZ_WQKVT;
static constexpr size_t OFF_WKVT = OFF_WPROJT + SZ_W768;
static constexpr size_t OFF_WQIT = OFF_WKVT + SZ_WKVT;
static constexpr size_t OFF_WPIT = OFF_WQIT + SZ_W768;
static constexpr size_t OFF_XB  = OFF_WPIT + SZ_W768;
static constexpr size_t OFF_YB  = OFF_XB + SZ_XB;
static constexpr size_t OFF_QB  = OFF_YB + SZ_YB;
static constexpr size_t OFF_KB  = OFF_QB + SZ_XB;
static constexpr size_t OFF_VB  = OFF_KB + SZ_XB;
static constexpr size_t OFF_XOUT = OFF_VB + SZ_XB;

extern "C" void kernel_launch(void* const* d_in, const int* in_sizes, int n_in,
                              void* d_out, int out_size, void* d_ws, size_t ws_size,
                              hipStream_t stream) {
  const float* x      = (const float*)d_in[0];
  const float* y      = (const float*)d_in[1];
  const float* y_mask = (const float*)d_in[2];
  const float* w_qkv  = (const float*)d_in[4];
  const float* w_proj = (const float*)d_in[5];
  const float* b_proj = (const float*)d_in[6];
  const float* w_kv   = (const float*)d_in[7];
  const float* w_qi   = (const float*)d_in[8];
  const float* w_pi   = (const float*)d_in[9];
  const float* b_pi   = (const float*)d_in[10];
  const float* alpha  = (const float*)d_in[11];
  const float* ln_g   = (const float*)d_in[12];
  const float* ln_b   = (const float*)d_in[13];
  float* out = (float*)d_out;
  char* ws = (char*)d_ws;

  us_t* wqkvT = (us_t*)(ws + OFF_WQKVT);
  us_t* wprojT = (us_t*)(ws + OFF_WPROJT);
  us_t* wkvT = (us_t*)(ws + OFF_WKVT);
  us_t* wqiT = (us_t*)(ws + OFF_WQIT);
  us_t* wpiT = (us_t*)(ws + OFF_WPIT);
  us_t* xb  = (us_t*)(ws + OFF_XB);
  us_t* yb  = (us_t*)(ws + OFF_YB);
  us_t* qb  = (us_t*)(ws + OFF_QB);
  us_t* kb  = (us_t*)(ws + OFF_KB);
  us_t* vb  = (us_t*)(ws + OFF_VB);
  float* xoutf = (float*)(ws + OFF_XOUT);
  us_t* attn_out = xb;                        // after QKV consumed xb
  us_t* lnout = qb;                           // after attention consumed q
  us_t* qib = kb;                             // after attention consumed k
  us_t* ktb = vb;                             // after attention consumed v (KVT runs post-attn)
  us_t* vtb = (us_t*)(ws + OFF_VB + SZ_KT);
  us_t* i2t_out = xb;                         // after XOUT consumed attn_out

  // 1) fused prep: 5 weight transposes + x/y conversion in one launch
  PrepJobs pj;
  pj.in[0] = w_qkv;  pj.out[0] = wqkvT;  pj.R[0] = 768; pj.C[0] = 2304;
  pj.in[1] = w_proj; pj.out[1] = wprojT; pj.R[1] = 768; pj.C[1] = 768;
  pj.in[2] = w_kv;   pj.out[2] = wkvT;   pj.R[2] = 512; pj.C[2] = 1536;
  pj.in[3] = w_qi;   pj.out[3] = wqiT;   pj.R[3] = 768; pj.C[3] = 768;
  pj.in[4] = w_pi;   pj.out[4] = wpiT;   pj.R[4] = 768; pj.C[4] = 768;
  pj.xin = x; pj.xout = xb; pj.n4x = MROWS * DD / 4;
  pj.yin = y; pj.yout = yb; pj.n4y = MTEXT * DT_ / 4;
  prep_all<<<dim3(72, 24, 6), 256, 0, stream>>>(pj);

  // 2) qkv projection (128x256 ring-2, r10-verified)
  EpiParams e1{}; e1.o0 = qb; e1.o1 = kb; e1.o2 = vb;
  gemm_w<<<dim3(9, 99), 512, 0, stream>>>(xb, wqkvT, MROWS, 768, e1);

  // 3) self attention (frame + cls merged)
  attn_all<<<864, 256, 0, stream>>>(qb, kb, vb, attn_out);

  // 4) out projection + bias -> x_out (fp32)  [one-barrier ring-3]
  EpiParams e2{}; e2.outf = xoutf; e2.bias = b_proj;
  gemm_bt<EPI_XOUT><<<dim3(6, 99), 256, 0, stream>>>(attn_out, wprojT, MROWS, 768, e2);

  // 5) LN -> bf16
  ln_kernel<<<MROWS, 256, 0, stream>>>(xoutf, ln_g, ln_b, lnout);

  // 6) q_i projection (scaled)  [one-barrier ring-3]
  EpiParams e3{}; e3.o0 = qib;
  gemm_bt<EPI_QI><<<dim3(6, 99), 256, 0, stream>>>(lnout, wqiT, MROWS, 768, e3);

  // 7) text kv projection (AFTER attention: vb is dead, alias legal)
  EpiParams e4{}; e4.o0 = ktb; e4.o1 = vtb;
  gemm_bt<EPI_KVT><<<dim3(12, 5), 256, 0, stream>>>(yb, wkvT, MTEXT, 512, e4);

  // 8) i2t cross attention
  i2t_attn<<<dim3(96 * 7), 256, 0, stream>>>(qib, ktb, vtb, y_mask, i2t_out);

  // 9) final projection + bias, fused d_out = x_out + alpha*yo  [one-barrier ring-3]
  EpiParams e5{}; e5.outf = out; e5.bias = b_pi; e5.aux = xoutf; e5.alphap = alpha;
  gemm_bt<EPI_FINAL><<<dim3(6, 99), 256, 0, stream>>>(i2t_out, wpiT, MROWS, 768, e5);
}